// Round 2
// baseline (81.588 us; speedup 1.0000x reference)
//
#include <hip/hip_runtime.h>

// Path signature depth-3, path (N=32, L=128, C=48) fp32 — fused single kernel.
//
// Math (R5/R9-validated, absmax 0.25):
//   v_t = p[t+1]-p[t], P_t[i] = p[t][i]-p[0][i],
//   G_t = P_t + v_t/2,  R_t = P_t/2 + v_t/6
//   S1 = p[127]-p[0];  S2[i,j] = sum_t G_t[i] v_t[j]   (register prefix a2)
//   S3[i,j,k] = sum_t (a2prefix + R_t[i] v_t[j]) v_t[k]
//   t-split x4 (32/32/32/31), Pi seeded globally per segment; exact fixup
//   S3 = sum_q [S3loc_q + a2pre_q (x) W_q], W_q = p[seg_end]-p[seg_start].
//
// R13 (R12 post-mortem): R12 regressed (15.6 us kernel) — 3-stage k-rotation
// + 2-deep float4 prefetch blew the 128-VGPR cap from launch_bounds(256,2)
// (spill/movs in hot loop). Model correction: VALU is per-SIMD (4/CU), LDS
// per-CU -> R11's pole is the LDS pipe (27.5k cyc worst-CU vs 12.8k VALU).
// This round: NO LDS in the main loop at all. v_j/v_k/v_i formed in regs as
// row-diffs of p from global (L1-resident, ~14 distinct lines/wave-iter).
// Two row-sets A/B only (depth-1 prefetch), hand-unrolled 2-step body
// (period-2 role swap, zero rotation movs), prefetch rows provably <=127
// (no clamp). v-staging phase + its barrier deleted. ~126 VGPR est.
// Bit-identical arithmetic (same subtraction). Predicted kernel ~9 us,
// total ~71-72 us.

#define N_BATCH 32
#define LPATH   128
#define T_STEPS 127
#define C       48
#define C2      2304
#define C3      110592
#define OUT_PER_N (C + C2 + C3)      // 112944
#define PATH_PER_N (LPATH * C)       // 6144
#define GROUPS 27                    // 1728 (i,jg,kc) units / 64 lanes
#define RSLOT 36                     // per-q slots/round: 4jj*8k + 4 a2
#define LDS_FLOATS 6912              // reduce scratch only: 3*36*64

typedef float f32x2 __attribute__((ext_vector_type(2)));

__global__ __launch_bounds__(256, 2) void sig_fused(const float* __restrict__ path,
                                                    float* __restrict__ out) {
    __shared__ float lds[LDS_FLOATS];

    int bid = blockIdx.x;
    int n = bid / GROUPS;
    int g = bid - n * GROUPS;
    int tid = threadIdx.x;
    int q = tid >> 6;                // t-segment 0..3
    int lane = tid & 63;

    const float* __restrict__ pb = path + n * PATH_PER_N;

    // S1 (once per batch)
    if (g == 0 && tid < C)
        out[(long)n * OUT_PER_N + tid] = pb[(LPATH - 1) * C + tid] - pb[tid];

    // unit U -> (i, jg, kc): U = i*36 + jg*6 + kc ; j = jg*8+[0,8), k = kc*8+[0,8)
    int U = g * 64 + lane;
    int i = U / 36;
    int rr = U - i * 36;
    int jg = rr / 6;
    int kc = rr - jg * 6;

    int T0 = q * 32;
    int T1 = (q == 3) ? T_STEPS : (T0 + 32);

    float Pi = pb[T0 * C + i] - pb[i];   // exact global prefix at segment start
    float a2[8];
    f32x2 s3[8][4];                      // packed k-pairs: [jj][kpair]
    #pragma unroll
    for (int jj = 0; jj < 8; ++jj) {
        a2[jj] = 0.f;
        #pragma unroll
        for (int p = 0; p < 4; ++p) s3[jj][p] = (f32x2){0.f, 0.f};
    }

    // ---- main loop: rows of p from global, v formed by register diff ----
    // State invariant at pair top: A = row t slices, B = row t+1 slices.
    const float* rj = pb + jg * 8;
    const float* rk = pb + kc * 8;
    const float* rip = pb + i;

    float4 Aj0 = *(const float4*)(rj + T0 * C);
    float4 Aj1 = *(const float4*)(rj + T0 * C + 4);
    float4 Ak0 = *(const float4*)(rk + T0 * C);
    float4 Ak1 = *(const float4*)(rk + T0 * C + 4);
    float  Ai  = rip[T0 * C];
    float4 Bj0 = *(const float4*)(rj + (T0 + 1) * C);
    float4 Bj1 = *(const float4*)(rj + (T0 + 1) * C + 4);
    float4 Bk0 = *(const float4*)(rk + (T0 + 1) * C);
    float4 Bk1 = *(const float4*)(rk + (T0 + 1) * C + 4);
    float  Bi  = rip[(T0 + 1) * C];

    // v = NEW - OLD; then prefetch row LT into the OLD slots (now dead).
#define SIGSTEP(OJ0, OJ1, OK0, OK1, OI, NJ0, NJ1, NK0, NK1, NI, LT, DOLOAD) do { \
        float vi_ = NI - OI;                                            \
        float G = Pi + 0.5f * vi_;                                      \
        float R = 0.5f * Pi + (1.0f / 6.0f) * vi_;                      \
        Pi += vi_;                                                      \
        f32x2 RG = {R, G};                                              \
        f32x2 kk0 = {NK0.x - OK0.x, NK0.y - OK0.y};                     \
        f32x2 kk1 = {NK0.z - OK0.z, NK0.w - OK0.w};                     \
        f32x2 kk2 = {NK1.x - OK1.x, NK1.y - OK1.y};                     \
        f32x2 kk3 = {NK1.z - OK1.z, NK1.w - OK1.w};                     \
        float vja[8] = {NJ0.x - OJ0.x, NJ0.y - OJ0.y,                   \
                        NJ0.z - OJ0.z, NJ0.w - OJ0.w,                   \
                        NJ1.x - OJ1.x, NJ1.y - OJ1.y,                   \
                        NJ1.z - OJ1.z, NJ1.w - OJ1.w};                  \
        if (DOLOAD) {                                                   \
            const float* nb_ = pb + (LT) * C;                           \
            OJ0 = *(const float4*)(nb_ + jg * 8);                       \
            OJ1 = *(const float4*)(nb_ + jg * 8 + 4);                   \
            OK0 = *(const float4*)(nb_ + kc * 8);                       \
            OK1 = *(const float4*)(nb_ + kc * 8 + 4);                   \
            OI  = nb_[i];                                               \
        }                                                               \
        _Pragma("unroll")                                               \
        for (int jj = 0; jj < 8; ++jj) {                                \
            f32x2 vjp = {vja[jj], vja[jj]};                             \
            f32x2 aap = {a2[jj], a2[jj]};                               \
            f32x2 t2v = __builtin_elementwise_fma(RG, vjp, aap);        \
            a2[jj] = t2v.y;                                             \
            f32x2 bb = {t2v.x, t2v.x};                                  \
            s3[jj][0] = __builtin_elementwise_fma(bb, kk0, s3[jj][0]);  \
            s3[jj][1] = __builtin_elementwise_fma(bb, kk1, s3[jj][1]);  \
            s3[jj][2] = __builtin_elementwise_fma(bb, kk2, s3[jj][2]);  \
            s3[jj][3] = __builtin_elementwise_fma(bb, kk3, s3[jj][3]);  \
        }                                                               \
    } while (0)

    int t = T0;
    for (; t + 1 < T1; t += 2) {
        // even: v_t = B - A, prefetch row t+2 -> A   (t+2 <= T1 <= 127)
        SIGSTEP(Aj0, Aj1, Ak0, Ak1, Ai, Bj0, Bj1, Bk0, Bk1, Bi, t + 2, 1);
        // odd:  v_{t+1} = A - B, prefetch row t+3 -> B (t+3 <= T1+1 <= 127 for q<3; <=127 for q==3)
        SIGSTEP(Bj0, Bj1, Bk0, Bk1, Bi, Aj0, Aj1, Ak0, Ak1, Ai, t + 3, 1);
    }
    if (t < T1)                       // q==3 tail (31st iter), no prefetch
        SIGSTEP(Aj0, Aj1, Ak0, Ak1, Ai, Bj0, Bj1, Bk0, Bk1, Bi, 0, 0);
#undef SIGSTEP

    // ---- W vectors for the fixup (wave 3 only; L1/L2-hot global reads) ----
    float4 W10, W11, W20, W21, W30, W31;
    if (q == 3) {
        float4 p32a = *(const float4*)(pb + 32 * C + kc * 8);
        float4 p32b = *(const float4*)(pb + 32 * C + kc * 8 + 4);
        float4 p64a = *(const float4*)(pb + 64 * C + kc * 8);
        float4 p64b = *(const float4*)(pb + 64 * C + kc * 8 + 4);
        float4 p96a = *(const float4*)(pb + 96 * C + kc * 8);
        float4 p96b = *(const float4*)(pb + 96 * C + kc * 8 + 4);
        float4 pEa  = *(const float4*)(pb + 127 * C + kc * 8);
        float4 pEb  = *(const float4*)(pb + 127 * C + kc * 8 + 4);
        W10 = make_float4(p64a.x - p32a.x, p64a.y - p32a.y, p64a.z - p32a.z, p64a.w - p32a.w);
        W11 = make_float4(p64b.x - p32b.x, p64b.y - p32b.y, p64b.z - p32b.z, p64b.w - p32b.w);
        W20 = make_float4(p96a.x - p64a.x, p96a.y - p64a.y, p96a.z - p64a.z, p96a.w - p64a.w);
        W21 = make_float4(p96b.x - p64b.x, p96b.y - p64b.y, p96b.z - p64b.z, p96b.w - p64b.w);
        W30 = make_float4(pEa.x - p96a.x, pEa.y - p96a.y, pEa.z - p96a.z, pEa.w - p96a.w);
        W31 = make_float4(pEb.x - p96b.x, pEb.y - p96b.y, pEb.z - p96b.z, pEb.w - p96b.w);
    }

    // ---- 2 rounds: waves 0-2 deposit 4 jj's, wave 3 combines + stores ----
    // (no pre-loop barrier needed: LDS untouched before the first deposit)
    long obase = (long)n * OUT_PER_N + C;
    #pragma unroll
    for (int r = 0; r < 2; ++r) {
        if (r) __syncthreads();      // protect previous round's reads
        if (q < 3) {
            float* dst = lds + (q * RSLOT) * 64 + lane;   // lane-major slots
            #pragma unroll
            for (int jjr = 0; jjr < 4; ++jjr) {
                int jj = r * 4 + jjr;
                dst[(jjr * 8 + 0) * 64] = s3[jj][0][0];
                dst[(jjr * 8 + 1) * 64] = s3[jj][0][1];
                dst[(jjr * 8 + 2) * 64] = s3[jj][1][0];
                dst[(jjr * 8 + 3) * 64] = s3[jj][1][1];
                dst[(jjr * 8 + 4) * 64] = s3[jj][2][0];
                dst[(jjr * 8 + 5) * 64] = s3[jj][2][1];
                dst[(jjr * 8 + 6) * 64] = s3[jj][3][0];
                dst[(jjr * 8 + 7) * 64] = s3[jj][3][1];
                dst[(32 + jjr) * 64]    = a2[jj];
            }
        }
        __syncthreads();
        if (q == 3) {
            #pragma unroll
            for (int jjr = 0; jjr < 4; ++jjr) {
                int jj = r * 4 + jjr;
                const float* s0 = lds + (0 * RSLOT) * 64 + lane;
                const float* s1 = lds + (1 * RSLOT) * 64 + lane;
                const float* s2 = lds + (2 * RSLOT) * 64 + lane;
                float a2q0 = s0[(32 + jjr) * 64];
                float a2q1 = s1[(32 + jjr) * 64];
                float a2q2 = s2[(32 + jjr) * 64];
                float pre1 = a2q0;
                float pre2 = a2q0 + a2q1;
                float pre3 = pre2 + a2q2;
                float acc[8];
                #pragma unroll
                for (int c = 0; c < 8; ++c) {
                    int sl = (jjr * 8 + c) * 64;
                    acc[c] = s0[sl] + s1[sl] + s2[sl];
                }
                acc[0] += s3[jj][0][0] + pre1 * W10.x + pre2 * W20.x + pre3 * W30.x;
                acc[1] += s3[jj][0][1] + pre1 * W10.y + pre2 * W20.y + pre3 * W30.y;
                acc[2] += s3[jj][1][0] + pre1 * W10.z + pre2 * W20.z + pre3 * W30.z;
                acc[3] += s3[jj][1][1] + pre1 * W10.w + pre2 * W20.w + pre3 * W30.w;
                acc[4] += s3[jj][2][0] + pre1 * W11.x + pre2 * W21.x + pre3 * W31.x;
                acc[5] += s3[jj][2][1] + pre1 * W11.y + pre2 * W21.y + pre3 * W31.y;
                acc[6] += s3[jj][3][0] + pre1 * W11.z + pre2 * W21.z + pre3 * W31.z;
                acc[7] += s3[jj][3][1] + pre1 * W11.w + pre2 * W21.w + pre3 * W31.w;

                float* dst = out + obase + C2 + (long)(i * C + jg * 8 + jj) * C + kc * 8;
                *(float4*)(dst)     = make_float4(acc[0], acc[1], acc[2], acc[3]);
                *(float4*)(dst + 4) = make_float4(acc[4], acc[5], acc[6], acc[7]);
                if (kc == 0)
                    out[obase + i * C + jg * 8 + jj] = pre3 + a2[jj];   // S2
            }
        }
    }
}

extern "C" void kernel_launch(void* const* d_in, const int* in_sizes, int n_in,
                              void* d_out, int out_size, void* d_ws, size_t ws_size,
                              hipStream_t stream) {
    const float* path = (const float*)d_in[0];
    float* out = (float*)d_out;
    (void)d_ws; (void)ws_size;

    sig_fused<<<N_BATCH * GROUPS, 256, 0, stream>>>(path, out);
}

// Round 3
// 75.397 us; speedup vs baseline: 1.0821x; 1.0821x over previous
//
#include <hip/hip_runtime.h>

// Path signature depth-3, path (N=32, L=128, C=48) fp32 — fused single kernel.
//
// Math (R5/R9-validated, absmax 0.25):
//   v_t = p[t+1]-p[t], P_t[i] = p[t][i]-p[0][i],
//   G_t = P_t + v_t/2,  R_t = P_t/2 + v_t/6
//   S1 = p[127]-p[0];  S2[i,j] = sum_t G_t[i] v_t[j]   (register prefix a2)
//   S3[i,j,k] = sum_t (a2prefix + R_t[i] v_t[j]) v_t[k]
//   t-split x4 (32/32/32/31), Pi seeded globally per segment; exact fixup
//   S3 = sum_q [S3loc_q + a2pre_q (x) W_q], W_q = p[seg_end]-p[seg_start].
//
// R14: post-mortems: R12 = rotation movs (unroll-2 didn't rename, +70 cyc/iter
// VALU -> 15.6us); R13 = consume-just-loaded (depth-1 trap -> ~full latency
// per step, 44.6k cyc = 18.6us). Pipe model stands: R11 is LDS-pipe-bound
// (27.5k cyc/CU worst = 11.5us of the 12.7us kernel). This round: k-stream
// only moved to global; j/i stay in LDS (proven). Period-4 slot rotation
// (A,B,C,D), hand-written 4-step block body -> zero movs; prefetch distance
// 3-4 iters (~300-400 cyc) covers L2 latency; k-prologue issued BEFORE the
// staging phase (staging+barrier hides first-use latency); max loaded row
// provably <=127 (q==3: 7 blocks + 3-iter no-load tail) -> no clamp, no OOB.
// LDS 27.5k -> 15.3k cyc/CU; VMEM ~5k (192B-contiguous wave footprint).
// ~105 VGPR < 128 cap. Bit-identical arithmetic. Predicted kernel ~9us,
// total ~71-73us. If regression: revert to R11, axis closed.

#define N_BATCH 32
#define LPATH   128
#define T_STEPS 127
#define C       48
#define C2      2304
#define C3      110592
#define OUT_PER_N (C + C2 + C3)      // 112944
#define PATH_PER_N (LPATH * C)       // 6144
#define GROUPS 27                    // 1728 (i,jg,kc) units / 64 lanes
#define RSLOT 36                     // per-q slots/round: 4jj*8k + 4 a2
#define LDS_FLOATS 6912              // max(v: 6096, reduce: 3*36*64=6912)

typedef float f32x2 __attribute__((ext_vector_type(2)));

__global__ __launch_bounds__(256, 2) void sig_fused(const float* __restrict__ path,
                                                    float* __restrict__ out) {
    __shared__ float lds[LDS_FLOATS];

    int bid = blockIdx.x;
    int n = bid / GROUPS;
    int g = bid - n * GROUPS;
    int tid = threadIdx.x;
    int q = tid >> 6;                // t-segment 0..3
    int lane = tid & 63;

    const float* __restrict__ pb = path + n * PATH_PER_N;

    // unit U -> (i, jg, kc): U = i*36 + jg*6 + kc ; j = jg*8+[0,8), k = kc*8+[0,8)
    int U = g * 64 + lane;
    int i = U / 36;
    int rr = U - i * 36;
    int jg = rr / 6;
    int kc = rr - jg * 6;

    int T0 = q * 32;

    // ---- k-stream prologue: rows T0..T0+3 issued FIRST (latency hidden
    //      under the staging phase + barrier) ----
    const float* gk = pb + T0 * C + kc * 8;
    float4 A0 = *(const float4*)(gk + 0 * C);
    float4 A1 = *(const float4*)(gk + 0 * C + 4);
    float4 B0 = *(const float4*)(gk + 1 * C);
    float4 B1 = *(const float4*)(gk + 1 * C + 4);
    float4 C0 = *(const float4*)(gk + 2 * C);
    float4 C1 = *(const float4*)(gk + 2 * C + 4);
    float4 D0 = *(const float4*)(gk + 3 * C);
    float4 D1 = *(const float4*)(gk + 3 * C + 4);
    gk += 4 * C;                     // now points at row T0+4

    // ---- stage v = diff(p) into LDS (coalesced float4) ----
    {
        const float4* p4 = (const float4*)pb;
        float4* v4 = (float4*)lds;
        #pragma unroll
        for (int c = 0; c < 6; ++c) {
            int idx = tid + 256 * c;
            if (idx < (T_STEPS * C) / 4) {            // 1524
                float4 a = p4[idx];
                float4 b = p4[idx + C / 4];
                v4[idx] = make_float4(b.x - a.x, b.y - a.y, b.z - a.z, b.w - a.w);
            }
        }
    }
    // S1 (once per batch), overlapped with staging
    if (g == 0 && tid < C)
        out[(long)n * OUT_PER_N + tid] = pb[(LPATH - 1) * C + tid] - pb[tid];
    __syncthreads();

    float Pi = pb[T0 * C + i] - pb[i];   // exact global prefix at segment start
    float a2[8];
    f32x2 s3[8][4];                      // packed k-pairs: [jj][kpair]
    #pragma unroll
    for (int jj = 0; jj < 8; ++jj) {
        a2[jj] = 0.f;
        #pragma unroll
        for (int p = 0; p < 4; ++p) s3[jj][p] = (f32x2){0.f, 0.f};
    }

    // ---- main loop: j/i from LDS (imm offsets), k from global (period-4
    //      slots, distance-3 prefetch, zero rotation movs) ----
    const float* ldsJ = lds + T0 * C + jg * 8;
    const float* ldsI = lds + T0 * C + i;

    // step: v_t from (N - O) rows; LDS v row at REL; then load row into O.
#define KSTEP(O0, O1, N0, N1, REL, DOLOAD) do {                         \
        float  vi_ = ldsI[(REL) * C];                                   \
        float4 vj0 = *(const float4*)(ldsJ + (REL) * C);                \
        float4 vj1 = *(const float4*)(ldsJ + (REL) * C + 4);            \
        f32x2 kk0 = {N0.x - O0.x, N0.y - O0.y};                         \
        f32x2 kk1 = {N0.z - O0.z, N0.w - O0.w};                         \
        f32x2 kk2 = {N1.x - O1.x, N1.y - O1.y};                         \
        f32x2 kk3 = {N1.z - O1.z, N1.w - O1.w};                         \
        if (DOLOAD) {                                                   \
            O0 = *(const float4*)(gk + (REL) * C);                      \
            O1 = *(const float4*)(gk + (REL) * C + 4);                  \
        }                                                               \
        float G = Pi + 0.5f * vi_;                                      \
        float R = 0.5f * Pi + (1.0f / 6.0f) * vi_;                      \
        Pi += vi_;                                                      \
        f32x2 RG = {R, G};                                              \
        float vja[8] = {vj0.x, vj0.y, vj0.z, vj0.w,                     \
                        vj1.x, vj1.y, vj1.z, vj1.w};                    \
        _Pragma("unroll")                                               \
        for (int jj = 0; jj < 8; ++jj) {                                \
            f32x2 vjp = {vja[jj], vja[jj]};                             \
            f32x2 aap = {a2[jj], a2[jj]};                               \
            f32x2 t2v = __builtin_elementwise_fma(RG, vjp, aap);        \
            a2[jj] = t2v.y;                                             \
            f32x2 bb = {t2v.x, t2v.x};                                  \
            s3[jj][0] = __builtin_elementwise_fma(bb, kk0, s3[jj][0]);  \
            s3[jj][1] = __builtin_elementwise_fma(bb, kk1, s3[jj][1]);  \
            s3[jj][2] = __builtin_elementwise_fma(bb, kk2, s3[jj][2]);  \
            s3[jj][3] = __builtin_elementwise_fma(bb, kk3, s3[jj][3]);  \
        }                                                               \
    } while (0)

    // q<3: 8 blocks of 4 (loads in last block harmlessly over-prefetch rows
    // <= T0+35 <= 99). q==3: 7 blocks (max loaded row = 127) + 3-iter tail
    // with no loads (slots already hold rows 124..127). Never reads past
    // row 127 -> no OOB, no clamp.
    int NB = (q == 3) ? 7 : 8;
    for (int b = 0; b < NB; ++b) {
        KSTEP(A0, A1, B0, B1, 0, 1);
        KSTEP(B0, B1, C0, C1, 1, 1);
        KSTEP(C0, C1, D0, D1, 2, 1);
        KSTEP(D0, D1, A0, A1, 3, 1);
        ldsJ += 4 * C; ldsI += 4 * C; gk += 4 * C;
    }
    if (q == 3) {                    // t = 124, 125, 126
        KSTEP(A0, A1, B0, B1, 0, 0);
        KSTEP(B0, B1, C0, C1, 1, 0);
        KSTEP(C0, C1, D0, D1, 2, 0);
    }
#undef KSTEP

    // ---- W vectors for the fixup (wave 3 only; L1/L2-hot global reads) ----
    float4 W10, W11, W20, W21, W30, W31;
    if (q == 3) {
        float4 p32a = *(const float4*)(pb + 32 * C + kc * 8);
        float4 p32b = *(const float4*)(pb + 32 * C + kc * 8 + 4);
        float4 p64a = *(const float4*)(pb + 64 * C + kc * 8);
        float4 p64b = *(const float4*)(pb + 64 * C + kc * 8 + 4);
        float4 p96a = *(const float4*)(pb + 96 * C + kc * 8);
        float4 p96b = *(const float4*)(pb + 96 * C + kc * 8 + 4);
        float4 pEa  = *(const float4*)(pb + 127 * C + kc * 8);
        float4 pEb  = *(const float4*)(pb + 127 * C + kc * 8 + 4);
        W10 = make_float4(p64a.x - p32a.x, p64a.y - p32a.y, p64a.z - p32a.z, p64a.w - p32a.w);
        W11 = make_float4(p64b.x - p32b.x, p64b.y - p32b.y, p64b.z - p32b.z, p64b.w - p32b.w);
        W20 = make_float4(p96a.x - p64a.x, p96a.y - p64a.y, p96a.z - p64a.z, p96a.w - p64a.w);
        W21 = make_float4(p96b.x - p64b.x, p96b.y - p64b.y, p96b.z - p64b.z, p96b.w - p64b.w);
        W30 = make_float4(pEa.x - p96a.x, pEa.y - p96a.y, pEa.z - p96a.z, pEa.w - p96a.w);
        W31 = make_float4(pEb.x - p96b.x, pEb.y - p96b.y, pEb.z - p96b.z, pEb.w - p96b.w);
    }

    __syncthreads();                 // all waves done reading v

    // ---- 2 rounds: waves 0-2 deposit 4 jj's, wave 3 combines + stores ----
    long obase = (long)n * OUT_PER_N + C;
    #pragma unroll
    for (int r = 0; r < 2; ++r) {
        if (r) __syncthreads();      // protect previous round's reads
        if (q < 3) {
            float* dst = lds + (q * RSLOT) * 64 + lane;   // lane-major slots
            #pragma unroll
            for (int jjr = 0; jjr < 4; ++jjr) {
                int jj = r * 4 + jjr;
                dst[(jjr * 8 + 0) * 64] = s3[jj][0][0];
                dst[(jjr * 8 + 1) * 64] = s3[jj][0][1];
                dst[(jjr * 8 + 2) * 64] = s3[jj][1][0];
                dst[(jjr * 8 + 3) * 64] = s3[jj][1][1];
                dst[(jjr * 8 + 4) * 64] = s3[jj][2][0];
                dst[(jjr * 8 + 5) * 64] = s3[jj][2][1];
                dst[(jjr * 8 + 6) * 64] = s3[jj][3][0];
                dst[(jjr * 8 + 7) * 64] = s3[jj][3][1];
                dst[(32 + jjr) * 64]    = a2[jj];
            }
        }
        __syncthreads();
        if (q == 3) {
            #pragma unroll
            for (int jjr = 0; jjr < 4; ++jjr) {
                int jj = r * 4 + jjr;
                const float* s0 = lds + (0 * RSLOT) * 64 + lane;
                const float* s1 = lds + (1 * RSLOT) * 64 + lane;
                const float* s2 = lds + (2 * RSLOT) * 64 + lane;
                float a2q0 = s0[(32 + jjr) * 64];
                float a2q1 = s1[(32 + jjr) * 64];
                float a2q2 = s2[(32 + jjr) * 64];
                float pre1 = a2q0;
                float pre2 = a2q0 + a2q1;
                float pre3 = pre2 + a2q2;
                float acc[8];
                #pragma unroll
                for (int c = 0; c < 8; ++c) {
                    int sl = (jjr * 8 + c) * 64;
                    acc[c] = s0[sl] + s1[sl] + s2[sl];
                }
                acc[0] += s3[jj][0][0] + pre1 * W10.x + pre2 * W20.x + pre3 * W30.x;
                acc[1] += s3[jj][0][1] + pre1 * W10.y + pre2 * W20.y + pre3 * W30.y;
                acc[2] += s3[jj][1][0] + pre1 * W10.z + pre2 * W20.z + pre3 * W30.z;
                acc[3] += s3[jj][1][1] + pre1 * W10.w + pre2 * W20.w + pre3 * W30.w;
                acc[4] += s3[jj][2][0] + pre1 * W11.x + pre2 * W21.x + pre3 * W31.x;
                acc[5] += s3[jj][2][1] + pre1 * W11.y + pre2 * W21.y + pre3 * W31.y;
                acc[6] += s3[jj][3][0] + pre1 * W11.z + pre2 * W21.z + pre3 * W31.z;
                acc[7] += s3[jj][3][1] + pre1 * W11.w + pre2 * W21.w + pre3 * W31.w;

                float* dst = out + obase + C2 + (long)(i * C + jg * 8 + jj) * C + kc * 8;
                *(float4*)(dst)     = make_float4(acc[0], acc[1], acc[2], acc[3]);
                *(float4*)(dst + 4) = make_float4(acc[4], acc[5], acc[6], acc[7]);
                if (kc == 0)
                    out[obase + i * C + jg * 8 + jj] = pre3 + a2[jj];   // S2
            }
        }
    }
}

extern "C" void kernel_launch(void* const* d_in, const int* in_sizes, int n_in,
                              void* d_out, int out_size, void* d_ws, size_t ws_size,
                              hipStream_t stream) {
    const float* path = (const float*)d_in[0];
    float* out = (float*)d_out;
    (void)d_ws; (void)ws_size;

    sig_fused<<<N_BATCH * GROUPS, 256, 0, stream>>>(path, out);
}